// Round 1
// baseline (89.624 us; speedup 1.0000x reference)
//
#include <hip/hip_runtime.h>
#include <math.h>

#define EPS 1e-7f

__device__ __forceinline__ float sigmoidf_(float x) { return 1.0f / (1.0f + expf(-x)); }

// One block per (image b, level). Computes the cell->gt assignment in LDS via
// atomicMax scatter, then streams all cells: BCE over obj logits for every
// cell, CIoU + IoU for positive cells. Block-reduces and does 4 atomics into ws.
__global__ __launch_bounds__(256) void det_loss_main(
    const float* __restrict__ pred0,
    const float* __restrict__ pred1,
    const float* __restrict__ pred2,
    const float* __restrict__ gt,     // (B,32,4)
    float* __restrict__ ws_f,         // [0]=bce_sum, [1]=box_sum (already /npos per image)
    int*   __restrict__ ws_i)         // [0]=total_pos, [1]=n_items
{
    __shared__ int   s_idx[52 * 52];   // max HW = 2704
    __shared__ float s_gt[32 * 4];
    __shared__ float s_red_f[8];       // 4 waves x {bce, box}
    __shared__ int   s_red_i[4];       // 4 waves x npos

    const int bid   = blockIdx.x;
    const int level = bid % 3;
    const int b     = bid / 3;

    const float* pred;
    int Wd;
    if (level == 0)      { pred = pred0; Wd = 52; }
    else if (level == 1) { pred = pred1; Wd = 26; }
    else                 { pred = pred2; Wd = 13; }
    const int   HW = Wd * Wd;
    const float S  = (float)Wd;       // IMG_SIZE / stride
    const float sc = 1.0f / S;        // stride / IMG_SIZE

    const int tid = threadIdx.x;

    if (tid < 128) s_gt[tid] = gt[b * 128 + tid];
    for (int i = tid; i < HW; i += 256) s_idx[i] = -1;
    __syncthreads();

    if (tid < 32) {
        const int n = tid;
        const float gx = s_gt[n * 4 + 0] * S;
        const float gy = s_gt[n * 4 + 1] * S;
        int col = (int)gx; col = min(max(col, 0), Wd - 1);
        int row = (int)gy; row = min(max(row, 0), Wd - 1);
        const float off_x = gx - (float)col;
        const float off_y = gy - (float)row;
        atomicMax(&s_idx[row * Wd + col], n);
        // x-neighbor
        {
            int col_n; bool vx;
            if (off_x < 0.5f) { col_n = col - 1; vx = (col > 0); }
            else              { col_n = col + 1; vx = (col < Wd - 1); }
            if (vx) atomicMax(&s_idx[row * Wd + col_n], n);
        }
        // y-neighbor
        {
            int row_n; bool vy;
            if (off_y < 0.5f) { row_n = row - 1; vy = (row > 0); }
            else              { row_n = row + 1; vy = (row < Wd - 1); }
            if (vy) atomicMax(&s_idx[row_n * Wd + col], n);
        }
    }
    __syncthreads();

    const float* base = pred + (size_t)b * 5 * HW;
    float bce = 0.0f, box = 0.0f;
    int npos = 0;

    for (int i = tid; i < HW; i += 256) {
        const float l0 = base[i];
        const int gi = s_idx[i];
        float obj_t = 0.0f;
        if (gi >= 0) {
            npos++;
            const float l1 = base[HW + i];
            const float l2 = base[2 * HW + i];
            const float l3 = base[3 * HW + i];
            const float l4 = base[4 * HW + i];
            const float ccol = (float)(i % Wd);
            const float crow = (float)(i / Wd);
            const float p_cx = (sigmoidf_(l1) * 2.0f - 0.5f + ccol) * sc;
            const float p_cy = (sigmoidf_(l2) * 2.0f - 0.5f + crow) * sc;
            const float p_w  = expf(fminf(fmaxf(l3, -5.0f), 5.0f)) * sc;
            const float p_h  = expf(fminf(fmaxf(l4, -5.0f), 5.0f)) * sc;
            const float t_cx = s_gt[gi * 4 + 0];
            const float t_cy = s_gt[gi * 4 + 1];
            const float t_w  = s_gt[gi * 4 + 2];
            const float t_h  = s_gt[gi * 4 + 3];

            const float b1x1 = p_cx - p_w * 0.5f, b1y1 = p_cy - p_h * 0.5f;
            const float b1x2 = p_cx + p_w * 0.5f, b1y2 = p_cy + p_h * 0.5f;
            const float b2x1 = t_cx - t_w * 0.5f, b2y1 = t_cy - t_h * 0.5f;
            const float b2x2 = t_cx + t_w * 0.5f, b2y2 = t_cy + t_h * 0.5f;

            const float w1 = b1x2 - b1x1, h1 = b1y2 - b1y1;
            const float w2 = b2x2 - b2x1, h2 = b2y2 - b2y1;

            const float iw = fmaxf(fminf(b1x2, b2x2) - fmaxf(b1x1, b2x1), 0.0f);
            const float ih = fmaxf(fminf(b1y2, b2y2) - fmaxf(b1y1, b2y1), 0.0f);
            const float inter = iw * ih;
            const float uni = w1 * h1 + w2 * h2 - inter + EPS;
            const float iou = inter / uni;

            const float cw = fmaxf(b1x2, b2x2) - fminf(b1x1, b2x1);
            const float ch = fmaxf(b1y2, b2y2) - fminf(b1y1, b2y1);
            const float c2 = cw * cw + ch * ch + EPS;
            const float dx = b2x1 + b2x2 - b1x1 - b1x2;
            const float dy = b2y1 + b2y2 - b1y1 - b1y2;
            const float rho2 = (dx * dx + dy * dy) * 0.25f;
            const float datan = atanf(w2 / (h2 + EPS)) - atanf(w1 / (h1 + EPS));
            const float v = (4.0f / (float)(M_PI * M_PI)) * datan * datan;
            const float alpha = v / (v - iou + 1.0f + EPS);
            const float ciou = 1.0f - iou + rho2 / c2 + alpha * v;
            box += fmaxf(ciou, 0.0f);

            // objectness target IoU (uses raw areas p_w*p_h, t_w*t_h)
            const float area_p = fmaxf(p_w * p_h, EPS);
            const float area_t = fmaxf(t_w * t_h, EPS);
            float iou2 = inter / (area_p + area_t - inter + EPS);
            iou2 = fminf(fmaxf(iou2, 0.0f), 1.0f);
            obj_t = iou2;
        }
        // stable BCE-with-logits
        bce += fmaxf(l0, 0.0f) - l0 * obj_t + log1pf(expf(-fabsf(l0)));
    }

    // wave (64-lane) reduce, then cross-wave via LDS
    for (int off = 32; off > 0; off >>= 1) {
        bce  += __shfl_down(bce, off);
        box  += __shfl_down(box, off);
        npos += __shfl_down(npos, off);
    }
    const int wave = tid >> 6;
    if ((tid & 63) == 0) {
        s_red_f[wave * 2 + 0] = bce;
        s_red_f[wave * 2 + 1] = box;
        s_red_i[wave] = npos;
    }
    __syncthreads();
    if (tid == 0) {
        float bce_t = 0.0f, box_t = 0.0f; int np_t = 0;
        for (int w = 0; w < 4; w++) {
            bce_t += s_red_f[w * 2 + 0];
            box_t += s_red_f[w * 2 + 1];
            np_t  += s_red_i[w];
        }
        atomicAdd(&ws_f[0], bce_t);
        atomicAdd(&ws_f[1], box_t / (float)max(np_t, 1));
        atomicAdd(&ws_i[0], np_t);
        if (np_t > 0) atomicAdd(&ws_i[1], 1);
    }
}

__global__ void det_loss_final(const float* __restrict__ ws_f,
                               const int* __restrict__ ws_i,
                               float* __restrict__ out)
{
    const float total_obj = ws_f[0] / fmaxf((float)ws_i[0], 1.0f);
    const float total_box = ws_f[1] / (float)max(ws_i[1], 1);
    out[0] = 1.0f * total_obj + 5.0f * total_box;
}

extern "C" void kernel_launch(void* const* d_in, const int* in_sizes, int n_in,
                              void* d_out, int out_size, void* d_ws, size_t ws_size,
                              hipStream_t stream)
{
    const float* pred0 = (const float*)d_in[0];
    const float* pred1 = (const float*)d_in[1];
    const float* pred2 = (const float*)d_in[2];
    const float* gt    = (const float*)d_in[3];
    float* out = (float*)d_out;

    const int B = in_sizes[3] / (32 * 4);   // 512

    float* ws_f = (float*)d_ws;             // [0]=bce, [1]=box
    int*   ws_i = (int*)((char*)d_ws + 8);  // [0]=total_pos, [1]=n_items

    hipMemsetAsync(d_ws, 0, 16, stream);
    det_loss_main<<<dim3(B * 3), dim3(256), 0, stream>>>(pred0, pred1, pred2, gt, ws_f, ws_i);
    det_loss_final<<<dim3(1), dim3(1), 0, stream>>>(ws_f, ws_i, out);
}

// Round 2
// 15.707 us; speedup vs baseline: 5.7060x; 5.7060x over previous
//
#include <hip/hip_runtime.h>
#include <math.h>

#define EPS 1e-7f
#define NB_BCE 1024   // blocks doing the BCE base-sum role

// BCE-with-logits base term (target-independent part): max(l,0) + log1p(exp(-|l|))
__device__ __forceinline__ float bce_base(float l) {
    return fmaxf(l, 0.0f) + __logf(1.0f + __expf(-fabsf(l)));
}

__device__ __forceinline__ float sigmoidf_(float x) { return 1.0f / (1.0f + expf(-x)); }

// Merged kernel.
//  blocks [0, NB_BCE)            : grid-stride BCE base sum over channel 0 of all
//                                  3 pyramid levels -> ws_c[bid]
//  blocks [NB_BCE, NB_BCE + 3B)  : per-(image,level) positive-cell work:
//                                  candidate scatter (<=96 cells), CIoU box loss,
//                                  obj_t BCE correction -> ws_box/ws_corr/ws_npos
__global__ __launch_bounds__(256) void det_main(
    const float* __restrict__ pred0,   // (B,5,52,52)
    const float* __restrict__ pred1,   // (B,5,26,26)
    const float* __restrict__ pred2,   // (B,5,13,13)
    const float* __restrict__ gt,      // (B,32,4)
    float* __restrict__ ws_c,          // [NB_BCE]
    float* __restrict__ ws_box,        // [3B]  (already / max(npos,1))
    float* __restrict__ ws_corr,       // [3B]  (sum of l0*obj_t)
    int*   __restrict__ ws_npos,       // [3B]
    int B)
{
    __shared__ int   s_map[52 * 52];
    __shared__ float s_gt[128];
    __shared__ int   s_cell[96];
    __shared__ float s_redf[8];
    __shared__ int   s_redi[4];

    const int tid = threadIdx.x;
    const int bid = blockIdx.x;

    if (bid < NB_BCE) {
        // ---------------- BCE base role ----------------
        const unsigned E0 = (unsigned)B * 2704u;            // level-0 cells
        const unsigned E1 = (unsigned)B * 676u;
        const unsigned E2 = (unsigned)B * 169u;
        const unsigned NV4 = (E0 + E1) >> 2;                // float4 items (both %4==0)
        float acc = 0.0f;

        for (unsigned v = (unsigned)bid * 256u + tid; v < NV4; v += NB_BCE * 256u) {
            const unsigned idx = v << 2;
            const float* p;
            if (idx < E0) {
                const unsigned b = idx / 2704u;
                const unsigned i = idx - b * 2704u;
                p = pred0 + (size_t)b * 13520u + i;
            } else {
                const unsigned j = idx - E0;
                const unsigned b = j / 676u;
                const unsigned i = j - b * 676u;
                p = pred1 + (size_t)b * 3380u + i;
            }
            const float4 l = *reinterpret_cast<const float4*>(p);
            acc += bce_base(l.x) + bce_base(l.y) + bce_base(l.z) + bce_base(l.w);
        }
        // level 2 (169 not %4) scalar
        for (unsigned j = (unsigned)bid * 256u + tid; j < E2; j += NB_BCE * 256u) {
            const unsigned b = j / 169u;
            const unsigned i = j - b * 169u;
            acc += bce_base(pred2[(size_t)b * 845u + i]);
        }

        // block reduce -> ws_c[bid]
        for (int off = 32; off > 0; off >>= 1) acc += __shfl_down(acc, off);
        if ((tid & 63) == 0) s_redf[tid >> 6] = acc;
        __syncthreads();
        if (tid == 0) ws_c[bid] = s_redf[0] + s_redf[1] + s_redf[2] + s_redf[3];
        return;
    }

    // ---------------- positives role ----------------
    const int pbid  = bid - NB_BCE;       // 0 .. 3B-1
    const int level = pbid % 3;
    const int b     = pbid / 3;

    const float* pred;
    int Wd;
    if (level == 0)      { pred = pred0; Wd = 52; }
    else if (level == 1) { pred = pred1; Wd = 26; }
    else                 { pred = pred2; Wd = 13; }
    const int   HW = Wd * Wd;
    const float S  = (float)Wd;
    const float sc = 1.0f / S;

    if (tid < 128) s_gt[tid] = gt[(size_t)b * 128 + tid];
    __syncthreads();

    // candidate generation: 32 gts -> up to 96 (cell, gi) entries; slot k has gi = k & 31
    if (tid < 32) {
        const int n = tid;
        const float gx = s_gt[n * 4 + 0] * S;
        const float gy = s_gt[n * 4 + 1] * S;
        int col = (int)gx; col = min(max(col, 0), Wd - 1);
        int row = (int)gy; row = min(max(row, 0), Wd - 1);
        const float off_x = gx - (float)col;
        const float off_y = gy - (float)row;
        s_cell[n] = row * Wd + col;
        int col_n, row_n; bool vx, vy;
        if (off_x < 0.5f) { col_n = col - 1; vx = (col > 0); }
        else              { col_n = col + 1; vx = (col < Wd - 1); }
        if (off_y < 0.5f) { row_n = row - 1; vy = (row > 0); }
        else              { row_n = row + 1; vy = (row < Wd - 1); }
        s_cell[32 + n] = vx ? (row * Wd + col_n) : -1;
        s_cell[64 + n] = vy ? (row_n * Wd + col) : -1;
    }
    __syncthreads();

    int c = -1;
    if (tid < 96) c = s_cell[tid];
    if (c >= 0) s_map[c] = -1;            // init only touched cells
    __syncthreads();
    if (c >= 0) atomicMax(&s_map[c], tid & 31);
    __syncthreads();

    // winner: unique slot per positive cell (max gi wins; ties impossible)
    const bool winner = (c >= 0) && (s_map[c] == (tid & 31));

    float box_v = 0.0f, corr_v = 0.0f;
    int np_v = 0;
    if (winner) {
        np_v = 1;
        const int gi = s_map[c];
        const float* base = pred + (size_t)b * 5 * HW;
        const float l0 = base[c];
        const float l1 = base[HW + c];
        const float l2 = base[2 * HW + c];
        const float l3 = base[3 * HW + c];
        const float l4 = base[4 * HW + c];
        const float ccol = (float)(c % Wd);
        const float crow = (float)(c / Wd);
        const float p_cx = (sigmoidf_(l1) * 2.0f - 0.5f + ccol) * sc;
        const float p_cy = (sigmoidf_(l2) * 2.0f - 0.5f + crow) * sc;
        const float p_w  = expf(fminf(fmaxf(l3, -5.0f), 5.0f)) * sc;
        const float p_h  = expf(fminf(fmaxf(l4, -5.0f), 5.0f)) * sc;
        const float t_cx = s_gt[gi * 4 + 0];
        const float t_cy = s_gt[gi * 4 + 1];
        const float t_w  = s_gt[gi * 4 + 2];
        const float t_h  = s_gt[gi * 4 + 3];

        const float b1x1 = p_cx - p_w * 0.5f, b1y1 = p_cy - p_h * 0.5f;
        const float b1x2 = p_cx + p_w * 0.5f, b1y2 = p_cy + p_h * 0.5f;
        const float b2x1 = t_cx - t_w * 0.5f, b2y1 = t_cy - t_h * 0.5f;
        const float b2x2 = t_cx + t_w * 0.5f, b2y2 = t_cy + t_h * 0.5f;

        const float w1 = b1x2 - b1x1, h1 = b1y2 - b1y1;
        const float w2 = b2x2 - b2x1, h2 = b2y2 - b2y1;

        const float iw = fmaxf(fminf(b1x2, b2x2) - fmaxf(b1x1, b2x1), 0.0f);
        const float ih = fmaxf(fminf(b1y2, b2y2) - fmaxf(b1y1, b2y1), 0.0f);
        const float inter = iw * ih;
        const float uni = w1 * h1 + w2 * h2 - inter + EPS;
        const float iou = inter / uni;

        const float cw = fmaxf(b1x2, b2x2) - fminf(b1x1, b2x1);
        const float ch = fmaxf(b1y2, b2y2) - fminf(b1y1, b2y1);
        const float c2 = cw * cw + ch * ch + EPS;
        const float dx = b2x1 + b2x2 - b1x1 - b1x2;
        const float dy = b2y1 + b2y2 - b1y1 - b1y2;
        const float rho2 = (dx * dx + dy * dy) * 0.25f;
        const float datan = atanf(w2 / (h2 + EPS)) - atanf(w1 / (h1 + EPS));
        const float v = (4.0f / (float)(M_PI * M_PI)) * datan * datan;
        const float alpha = v / (v - iou + 1.0f + EPS);
        const float ciou = 1.0f - iou + rho2 / c2 + alpha * v;
        box_v = fmaxf(ciou, 0.0f);

        const float area_p = fmaxf(p_w * p_h, EPS);
        const float area_t = fmaxf(t_w * t_h, EPS);
        float iou2 = inter / (area_p + area_t - inter + EPS);
        iou2 = fminf(fmaxf(iou2, 0.0f), 1.0f);
        corr_v = l0 * iou2;               // BCE correction term: -sum(l0*obj_t)
    }

    for (int off = 32; off > 0; off >>= 1) {
        box_v  += __shfl_down(box_v, off);
        corr_v += __shfl_down(corr_v, off);
        np_v   += __shfl_down(np_v, off);
    }
    const int wave = tid >> 6;
    if ((tid & 63) == 0) {
        s_redf[wave * 2 + 0] = box_v;
        s_redf[wave * 2 + 1] = corr_v;
        s_redi[wave] = np_v;
    }
    __syncthreads();
    if (tid == 0) {
        float box_t = 0.0f, corr_t = 0.0f; int np_t = 0;
        for (int w = 0; w < 4; w++) {
            box_t  += s_redf[w * 2 + 0];
            corr_t += s_redf[w * 2 + 1];
            np_t   += s_redi[w];
        }
        ws_box[pbid]  = box_t / (float)max(np_t, 1);
        ws_corr[pbid] = corr_t;
        ws_npos[pbid] = np_t;
    }
}

__global__ __launch_bounds__(256) void det_final(
    const float* __restrict__ ws_c,
    const float* __restrict__ ws_box,
    const float* __restrict__ ws_corr,
    const int*   __restrict__ ws_npos,
    int nPL,                              // 3B
    float* __restrict__ out)
{
    __shared__ float s_f[12];
    __shared__ int   s_i[8];
    const int tid = threadIdx.x;
    float box = 0.0f, corr = 0.0f, bce = 0.0f;
    int pos = 0, items = 0;
    for (int i = tid; i < nPL; i += 256) {
        box  += ws_box[i];
        corr += ws_corr[i];
        const int np = ws_npos[i];
        pos += np;
        items += (np > 0) ? 1 : 0;
    }
    for (int i = tid; i < NB_BCE; i += 256) bce += ws_c[i];

    for (int off = 32; off > 0; off >>= 1) {
        box  += __shfl_down(box, off);
        corr += __shfl_down(corr, off);
        bce  += __shfl_down(bce, off);
        pos  += __shfl_down(pos, off);
        items += __shfl_down(items, off);
    }
    const int wave = tid >> 6;
    if ((tid & 63) == 0) {
        s_f[wave * 3 + 0] = box;
        s_f[wave * 3 + 1] = corr;
        s_f[wave * 3 + 2] = bce;
        s_i[wave * 2 + 0] = pos;
        s_i[wave * 2 + 1] = items;
    }
    __syncthreads();
    if (tid == 0) {
        float box_t = 0.0f, corr_t = 0.0f, bce_t = 0.0f;
        int pos_t = 0, it_t = 0;
        for (int w = 0; w < 4; w++) {
            box_t  += s_f[w * 3 + 0];
            corr_t += s_f[w * 3 + 1];
            bce_t  += s_f[w * 3 + 2];
            pos_t  += s_i[w * 2 + 0];
            it_t   += s_i[w * 2 + 1];
        }
        const float total_obj = (bce_t - corr_t) / fmaxf((float)pos_t, 1.0f);
        const float total_box = box_t / (float)max(it_t, 1);
        out[0] = total_obj + 5.0f * total_box;
    }
}

extern "C" void kernel_launch(void* const* d_in, const int* in_sizes, int n_in,
                              void* d_out, int out_size, void* d_ws, size_t ws_size,
                              hipStream_t stream)
{
    const float* pred0 = (const float*)d_in[0];
    const float* pred1 = (const float*)d_in[1];
    const float* pred2 = (const float*)d_in[2];
    const float* gt    = (const float*)d_in[3];
    float* out = (float*)d_out;

    const int B   = in_sizes[3] / (32 * 4);   // 512
    const int nPL = 3 * B;                    // 1536

    // ws layout (floats): ws_c[NB_BCE] | ws_box[nPL] | ws_corr[nPL] | ws_npos[nPL](int)
    float* ws_c    = (float*)d_ws;
    float* ws_box  = ws_c + NB_BCE;
    float* ws_corr = ws_box + nPL;
    int*   ws_npos = (int*)(ws_corr + nPL);

    det_main<<<dim3(NB_BCE + nPL), dim3(256), 0, stream>>>(
        pred0, pred1, pred2, gt, ws_c, ws_box, ws_corr, ws_npos, B);
    det_final<<<dim3(1), dim3(256), 0, stream>>>(ws_c, ws_box, ws_corr, ws_npos, nPL, out);
}